// Round 2
// baseline (3401.525 us; speedup 1.0000x reference)
//
#include <hip/hip_runtime.h>
#include <hip/hip_bf16.h>

#define DD 2048
#define NF 24
#define NROWS 4096
#define VOCAB_N 32000
#define EPS_F 1.1920929e-07f

typedef __attribute__((ext_vector_type(8))) __bf16 bf16x8;
typedef __attribute__((ext_vector_type(4))) float f32x4;

__device__ __forceinline__ unsigned short f2bf(float f) {
  union { float f; unsigned int u; } v; v.f = f;
  unsigned int r = v.u + 0x7fffu + ((v.u >> 16) & 1u);  // RNE
  return (unsigned short)(r >> 16);
}

__device__ __forceinline__ void gload_lds16(const void* g, void* l) {
  __builtin_amdgcn_global_load_lds(
      (const __attribute__((address_space(1))) void*)g,
      (__attribute__((address_space(3))) void*)l, 16, 0, 0);
}

// ---------------- embedding gather ----------------
__global__ __launch_bounds__(256) void k_gather(const int* __restrict__ tok,
                                                const float* __restrict__ embed,
                                                float* __restrict__ x) {
  const int row = blockIdx.x;
  const int t = tok[row];
  const float4* s = (const float4*)(embed + (size_t)t * DD);
  float4* d = (float4*)(x + (size_t)row * DD);
  d[threadIdx.x] = s[threadIdx.x];
  d[threadIdx.x + 256] = s[threadIdx.x + 256];
}

// ---------------- W reconstruction (unchanged) ----------------
__global__ __launch_bounds__(256) void k_wrec(
    const float* __restrict__ hr, const float* __restrict__ hi,
    const float* __restrict__ kar, const float* __restrict__ kai,
    const float* __restrict__ kbr, const float* __restrict__ kbi,
    const float* __restrict__ scale, unsigned short* __restrict__ W) {
  __shared__ float HR[64][64], HI[64][64];
  __shared__ float AR[16][64], AI[16][64], BR[16][64], BI[16][64];
  const int e0 = blockIdx.x * 64, d0 = blockIdx.y * 64;
  const int tid = threadIdx.x;
  {
    const int r = tid >> 2, cbase = (tid & 3) * 16;
#pragma unroll
    for (int j = 0; j < 4; ++j) {
      const int c = cbase + j * 4;
      *(float4*)&HR[r][c] = *(const float4*)&hr[(size_t)(e0 + r) * DD + d0 + c];
      *(float4*)&HI[r][c] = *(const float4*)&hi[(size_t)(e0 + r) * DD + d0 + c];
    }
  }
  const int te = tid >> 4, td = tid & 15;
  for (int f = 0; f < NF; ++f) {
    __syncthreads();
    {
      const int r = tid >> 4, c = (tid & 15) * 4;
      const size_t ga = ((size_t)f * 16 + r) * DD;
      *(float4*)&AR[r][c] = *(const float4*)&kar[ga + e0 + c];
      *(float4*)&AI[r][c] = *(const float4*)&kai[ga + e0 + c];
      *(float4*)&BR[r][c] = *(const float4*)&kbr[ga + d0 + c];
      *(float4*)&BI[r][c] = *(const float4*)&kbi[ga + d0 + c];
    }
    __syncthreads();
    float pr[4][4], pi[4][4];
#pragma unroll
    for (int i = 0; i < 4; ++i)
#pragma unroll
      for (int j = 0; j < 4; ++j) { pr[i][j] = 0.f; pi[i][j] = 0.f; }
#pragma unroll 4
    for (int r = 0; r < 16; ++r) {
      float ar[4], ai[4], br[4], bi[4];
      *(float4*)ar = *(const float4*)&AR[r][te * 4];
      *(float4*)ai = *(const float4*)&AI[r][te * 4];
      *(float4*)br = *(const float4*)&BR[r][td * 4];
      *(float4*)bi = *(const float4*)&BI[r][td * 4];
#pragma unroll
      for (int i = 0; i < 4; ++i)
#pragma unroll
        for (int j = 0; j < 4; ++j) {
          pr[i][j] += ar[i] * br[j] + ai[i] * bi[j];
          pi[i][j] += ai[i] * br[j] - ar[i] * bi[j];
        }
    }
    const float sc = scale[f];
#pragma unroll
    for (int i = 0; i < 4; ++i) {
      const int e = te * 4 + i;
      ushort4 o;
      float w0 = (HR[e][td * 4 + 0] * pr[i][0] - HI[e][td * 4 + 0] * pi[i][0]) * sc;
      float w1 = (HR[e][td * 4 + 1] * pr[i][1] - HI[e][td * 4 + 1] * pi[i][1]) * sc;
      float w2 = (HR[e][td * 4 + 2] * pr[i][2] - HI[e][td * 4 + 2] * pi[i][2]) * sc;
      float w3 = (HR[e][td * 4 + 3] * pr[i][3] - HI[e][td * 4 + 3] * pi[i][3]) * sc;
      o.x = f2bf(w0); o.y = f2bf(w1); o.z = f2bf(w2); o.w = f2bf(w3);
      *(ushort4*)&W[((size_t)f * DD + e0 + e) * DD + d0 + td * 4] = o;
    }
  }
}

// ---------------- rmsnorm ----------------
__global__ __launch_bounds__(256) void k_rmsnorm(const float* __restrict__ x,
                                                 const float* __restrict__ w,
                                                 unsigned short* __restrict__ h) {
  const int row = blockIdx.x, tid = threadIdx.x;
  const float4* xr = (const float4*)(x + (size_t)row * DD);
  const float4 a = xr[tid], b = xr[tid + 256];
  float s = a.x * a.x + a.y * a.y + a.z * a.z + a.w * a.w +
            b.x * b.x + b.y * b.y + b.z * b.z + b.w * b.w;
#pragma unroll
  for (int m = 32; m; m >>= 1) s += __shfl_xor(s, m);
  __shared__ float part[4];
  if ((tid & 63) == 0) part[tid >> 6] = s;
  __syncthreads();
  const float inv = rsqrtf((part[0] + part[1] + part[2] + part[3]) * (1.f / DD) + EPS_F);
  const float4* wr = (const float4*)w;
  const float4 w0 = wr[tid], w1 = wr[tid + 256];
  ushort4 o0, o1;
  o0.x = f2bf(a.x * inv * w0.x); o0.y = f2bf(a.y * inv * w0.y);
  o0.z = f2bf(a.z * inv * w0.z); o0.w = f2bf(a.w * inv * w0.w);
  o1.x = f2bf(b.x * inv * w1.x); o1.y = f2bf(b.y * inv * w1.y);
  o1.z = f2bf(b.z * inv * w1.z); o1.w = f2bf(b.w * inv * w1.w);
  ushort4* hd = (ushort4*)(h + (size_t)row * DD);
  hd[tid] = o0;
  hd[tid + 256] = o1;
}

// ---------------- 8-phase GEMM: out[t][n] (+)= act( sum_k A[t][k]*B[n][k] ) ----------------
// BM=128, BN=256, BK=64, 8 waves (2Mx4N), per-wave 64x64. K fixed = 2048 (32 K-tiles).
// LDS: A dbuf 2x16KB, B dbuf 2x32KB = 96KB. XOR-swizzle pslot = kslot ^ (row&7) applied
// on the pre-swizzled global source (linear global_load_lds dest) and on ds_read addrs.
// 4 phases/K-tile: P_ni = {ds_read B[ni] (+A all at P0); stage one slot; bar; MFMA x8; bar}.
// Counted vmcnt(2) once per K-tile at P3 BEFORE the final barrier (never 0 in steady state).
// ACT: 0 = C += v, 1 = C += silu(v), 2 = C = v
template <int ACT>
__global__ __launch_bounds__(512, 2) void k_gemm8(const unsigned short* __restrict__ A,
                                                  const unsigned short* __restrict__ B,
                                                  float* __restrict__ C, const int ldc) {
  __shared__ unsigned short lsA[2][8192];   // [dbuf][128 rows][64 k] swizzled
  __shared__ unsigned short lsB[2][16384];  // [dbuf][256 rows][64 k] swizzled
  const int tid = threadIdx.x;
  const int lane = tid & 63;
  const int wave = tid >> 6;
  const int wm = wave >> 2, wn = wave & 3;
  // bijective XCD swizzle (gridDim.x % 8 == 0 for both grids)
  const int bid = blockIdx.x;
  const int swz = (bid & 7) * (gridDim.x >> 3) + (bid >> 3);
  const int t0 = (swz & 31) * 128;   // M/BM == 32 for both GEMM shapes
  const int n0 = (swz >> 5) * 256;
  const unsigned short* Ab = A + (size_t)t0 * DD;
  const unsigned short* Bb = B + (size_t)n0 * DD;
  const int srow = tid >> 3;                    // staging row 0..63
  const int kslot = (tid & 7) ^ (srow & 7);     // pre-swizzled source k-slot
  const int fr = lane & 15, g = lane >> 4, e8 = fr & 7;
  const int arow0 = (wm * 64 + fr) * 64;        // element offsets
  const int brow0 = (wn * 64 + fr) * 64;

#define STAGE_A(q, kt)                                                                    \
  {                                                                                       \
    gload_lds16(Ab + (size_t)srow * DD + (kt) * 64 + kslot * 8,        &lsA[q][tid * 8]); \
    gload_lds16(Ab + (size_t)(srow + 64) * DD + (kt) * 64 + kslot * 8,                    \
                &lsA[q][4096 + tid * 8]);                                                 \
  }
#define STAGE_B(q, h, kt)                                                                 \
  {                                                                                       \
    gload_lds16(Bb + (size_t)((h) * 128 + srow) * DD + (kt) * 64 + kslot * 8,             \
                &lsB[q][(h) * 8192 + tid * 8]);                                           \
    gload_lds16(Bb + (size_t)((h) * 128 + 64 + srow) * DD + (kt) * 64 + kslot * 8,        \
                &lsB[q][(h) * 8192 + 4096 + tid * 8]);                                    \
  }

  f32x4 acc[4][4];
#pragma unroll
  for (int i = 0; i < 4; ++i)
#pragma unroll
    for (int j = 0; j < 4; ++j) acc[i][j] = (f32x4){0.f, 0.f, 0.f, 0.f};

  // prologue: tile 0 fully + A(1); allow A(1)'s 2 loads outstanding
  STAGE_A(0, 0);
  STAGE_B(0, 0, 0);
  STAGE_B(0, 1, 0);
  STAGE_A(1, 1);
  asm volatile("s_waitcnt vmcnt(2)" ::: "memory");
  __builtin_amdgcn_s_barrier();

  const int NT = DD / 64;  // 32 K-tiles
  for (int t = 0; t < NT; ++t) {
    const int q = t & 1;
    bf16x8 af[2][4], bg[2];
    // ---- P0: read all A frags + B[ni=0]; MFMA ni=0 ----
#pragma unroll
    for (int ks = 0; ks < 2; ++ks)
#pragma unroll
      for (int mi = 0; mi < 4; ++mi)
        af[ks][mi] = *(const bf16x8*)&lsA[q][arow0 + mi * 1024 + ((((ks << 2) + g) ^ e8) << 3)];
#pragma unroll
    for (int ks = 0; ks < 2; ++ks)
      bg[ks] = *(const bf16x8*)&lsB[q][brow0 + ((((ks << 2) + g) ^ e8) << 3)];
    __builtin_amdgcn_s_barrier();
    __builtin_amdgcn_s_setprio(1);
#pragma unroll
    for (int ks = 0; ks < 2; ++ks)
#pragma unroll
      for (int mi = 0; mi < 4; ++mi)
        acc[mi][0] = __builtin_amdgcn_mfma_f32_16x16x32_bf16(af[ks][mi], bg[ks], acc[mi][0], 0, 0, 0);
    __builtin_amdgcn_s_setprio(0);
    __builtin_amdgcn_s_barrier();
    // ---- P1..P3 ----
#pragma unroll
    for (int ni = 1; ni < 4; ++ni) {
#pragma unroll
      for (int ks = 0; ks < 2; ++ks)
        bg[ks] = *(const bf16x8*)&lsB[q][brow0 + ni * 1024 + ((((ks << 2) + g) ^ e8) << 3)];
      if (ni == 1) {
        if (t + 1 < NT) STAGE_B(q ^ 1, 0, t + 1);
      } else if (ni == 2) {
        if (t + 1 < NT) STAGE_B(q ^ 1, 1, t + 1);
      } else {
        if (t + 2 < NT) STAGE_A(q, t + 2);  // (t+2)&1 == q; lsA[q] dead since P0
      }
      __builtin_amdgcn_s_barrier();
      __builtin_amdgcn_s_setprio(1);
#pragma unroll
      for (int ks = 0; ks < 2; ++ks)
#pragma unroll
        for (int mi = 0; mi < 4; ++mi)
          acc[mi][ni] = __builtin_amdgcn_mfma_f32_16x16x32_bf16(af[ks][mi], bg[ks], acc[mi][ni], 0, 0, 0);
      __builtin_amdgcn_s_setprio(0);
      if (ni == 3) {
        // drain so B0(t+1),B1(t+1) landed before the barrier; keep A(t+2) in flight
        if (t + 2 < NT) asm volatile("s_waitcnt vmcnt(2)" ::: "memory");
        else            asm volatile("s_waitcnt vmcnt(0)" ::: "memory");
      }
      __builtin_amdgcn_s_barrier();
    }
  }
#undef STAGE_A
#undef STAGE_B

  const int orow = t0 + wm * 64 + g * 4;
  const int ocol = n0 + wn * 64 + fr;
#pragma unroll
  for (int mi = 0; mi < 4; ++mi)
#pragma unroll
    for (int ni = 0; ni < 4; ++ni)
#pragma unroll
      for (int j = 0; j < 4; ++j) {
        const size_t idx = (size_t)(orow + mi * 16 + j) * ldc + (ocol + ni * 16);
        const float v = acc[mi][ni][j];
        if (ACT == 0)      C[idx] += v;
        else if (ACT == 1) C[idx] += v / (1.f + __expf(-v));
        else               C[idx] = v;
      }
}

// ---------------- f32 -> bf16 bulk convert ----------------
__global__ void k_cvt(const float* __restrict__ in, unsigned short* __restrict__ out, int n4) {
  int i = blockIdx.x * blockDim.x + threadIdx.x;
  const int stride = gridDim.x * blockDim.x;
  for (; i < n4; i += stride) {
    const float4 v = ((const float4*)in)[i];
    ushort4 o;
    o.x = f2bf(v.x); o.y = f2bf(v.y); o.z = f2bf(v.z); o.w = f2bf(v.w);
    ((ushort4*)out)[i] = o;
  }
}

extern "C" void kernel_launch(void* const* d_in, const int* in_sizes, int n_in,
                              void* d_out, int out_size, void* d_ws, size_t ws_size,
                              hipStream_t stream) {
  (void)in_sizes; (void)n_in; (void)out_size; (void)ws_size;
  const int* tokens = (const int*)d_in[0];
  const float* hr = (const float*)d_in[1];
  const float* hi = (const float*)d_in[2];
  const float* kar = (const float*)d_in[3];
  const float* kai = (const float*)d_in[4];
  const float* kbr = (const float*)d_in[5];
  const float* kbi = (const float*)d_in[6];
  const float* lscale = (const float*)d_in[7];
  const float* norm_w = (const float*)d_in[8];
  const float* embed = (const float*)d_in[9];
  const float* lm = (const float*)d_in[10];
  const float* fnw = (const float*)d_in[11];
  float* out = (float*)d_out;
  char* ws = (char*)d_ws;

  // ws layout: W bf16 [24][2048][2048] @0 (192 MiB); h bf16 [4096][2048] after.
  // lm_bf16 overlays W (dead after last layer). x (f32) lives in d_out (dead
  // before the final GEMM overwrites all of d_out).
  unsigned short* W = (unsigned short*)ws;
  unsigned short* h = (unsigned short*)(ws + 201326592);
  unsigned short* lmb = W;
  float* x = out;

  k_gather<<<NROWS, 256, 0, stream>>>(tokens, embed, x);
  k_wrec<<<dim3(32, 32), 256, 0, stream>>>(hr, hi, kar, kai, kbr, kbi, lscale, W);
  for (int l = 0; l < 12; ++l) {
    k_rmsnorm<<<NROWS, 256, 0, stream>>>(x, norm_w + (size_t)l * 2 * DD, h);
    k_gemm8<0><<<256, 512, 0, stream>>>(h, W + (size_t)(2 * l) * DD * DD, x, DD);
    k_rmsnorm<<<NROWS, 256, 0, stream>>>(x, norm_w + (size_t)l * 2 * DD + DD, h);
    k_gemm8<1><<<256, 512, 0, stream>>>(h, W + (size_t)(2 * l + 1) * DD * DD, x, DD);
  }
  k_rmsnorm<<<NROWS, 256, 0, stream>>>(x, fnw, h);
  k_cvt<<<2048, 256, 0, stream>>>(lm, lmb, VOCAB_N * DD / 4);
  k_gemm8<2><<<4000, 512, 0, stream>>>(h, lmb, out, VOCAB_N);
}

// Round 3
// 2995.928 us; speedup vs baseline: 1.1354x; 1.1354x over previous
//
#include <hip/hip_runtime.h>
#include <hip/hip_bf16.h>

#define DD 2048
#define NF 24
#define NROWS 4096
#define VOCAB_N 32000
#define EPS_F 1.1920929e-07f

typedef __attribute__((ext_vector_type(8))) __bf16 bf16x8;
typedef __attribute__((ext_vector_type(4))) float f32x4;

__device__ __forceinline__ unsigned short f2bf(float f) {
  union { float f; unsigned int u; } v; v.f = f;
  unsigned int r = v.u + 0x7fffu + ((v.u >> 16) & 1u);  // RNE
  return (unsigned short)(r >> 16);
}

__device__ __forceinline__ void gload_lds16(const void* g, void* l) {
  __builtin_amdgcn_global_load_lds(
      (const __attribute__((address_space(1))) void*)g,
      (__attribute__((address_space(3))) void*)l, 16, 0, 0);
}

// ---------------- embedding gather ----------------
__global__ __launch_bounds__(256) void k_gather(const int* __restrict__ tok,
                                                const float* __restrict__ embed,
                                                float* __restrict__ x) {
  const int row = blockIdx.x;
  const int t = tok[row];
  const float4* s = (const float4*)(embed + (size_t)t * DD);
  float4* d = (float4*)(x + (size_t)row * DD);
  d[threadIdx.x] = s[threadIdx.x];
  d[threadIdx.x + 256] = s[threadIdx.x + 256];
}

// ---------------- W reconstruction (unchanged) ----------------
__global__ __launch_bounds__(256) void k_wrec(
    const float* __restrict__ hr, const float* __restrict__ hi,
    const float* __restrict__ kar, const float* __restrict__ kai,
    const float* __restrict__ kbr, const float* __restrict__ kbi,
    const float* __restrict__ scale, unsigned short* __restrict__ W) {
  __shared__ float HR[64][64], HI[64][64];
  __shared__ float AR[16][64], AI[16][64], BR[16][64], BI[16][64];
  const int e0 = blockIdx.x * 64, d0 = blockIdx.y * 64;
  const int tid = threadIdx.x;
  {
    const int r = tid >> 2, cbase = (tid & 3) * 16;
#pragma unroll
    for (int j = 0; j < 4; ++j) {
      const int c = cbase + j * 4;
      *(float4*)&HR[r][c] = *(const float4*)&hr[(size_t)(e0 + r) * DD + d0 + c];
      *(float4*)&HI[r][c] = *(const float4*)&hi[(size_t)(e0 + r) * DD + d0 + c];
    }
  }
  const int te = tid >> 4, td = tid & 15;
  for (int f = 0; f < NF; ++f) {
    __syncthreads();
    {
      const int r = tid >> 4, c = (tid & 15) * 4;
      const size_t ga = ((size_t)f * 16 + r) * DD;
      *(float4*)&AR[r][c] = *(const float4*)&kar[ga + e0 + c];
      *(float4*)&AI[r][c] = *(const float4*)&kai[ga + e0 + c];
      *(float4*)&BR[r][c] = *(const float4*)&kbr[ga + d0 + c];
      *(float4*)&BI[r][c] = *(const float4*)&kbi[ga + d0 + c];
    }
    __syncthreads();
    float pr[4][4], pi[4][4];
#pragma unroll
    for (int i = 0; i < 4; ++i)
#pragma unroll
      for (int j = 0; j < 4; ++j) { pr[i][j] = 0.f; pi[i][j] = 0.f; }
#pragma unroll 4
    for (int r = 0; r < 16; ++r) {
      float ar[4], ai[4], br[4], bi[4];
      *(float4*)ar = *(const float4*)&AR[r][te * 4];
      *(float4*)ai = *(const float4*)&AI[r][te * 4];
      *(float4*)br = *(const float4*)&BR[r][td * 4];
      *(float4*)bi = *(const float4*)&BI[r][td * 4];
#pragma unroll
      for (int i = 0; i < 4; ++i)
#pragma unroll
        for (int j = 0; j < 4; ++j) {
          pr[i][j] += ar[i] * br[j] + ai[i] * bi[j];
          pi[i][j] += ai[i] * br[j] - ar[i] * bi[j];
        }
    }
    const float sc = scale[f];
#pragma unroll
    for (int i = 0; i < 4; ++i) {
      const int e = te * 4 + i;
      ushort4 o;
      float w0 = (HR[e][td * 4 + 0] * pr[i][0] - HI[e][td * 4 + 0] * pi[i][0]) * sc;
      float w1 = (HR[e][td * 4 + 1] * pr[i][1] - HI[e][td * 4 + 1] * pi[i][1]) * sc;
      float w2 = (HR[e][td * 4 + 2] * pr[i][2] - HI[e][td * 4 + 2] * pi[i][2]) * sc;
      float w3 = (HR[e][td * 4 + 3] * pr[i][3] - HI[e][td * 4 + 3] * pi[i][3]) * sc;
      o.x = f2bf(w0); o.y = f2bf(w1); o.z = f2bf(w2); o.w = f2bf(w3);
      *(ushort4*)&W[((size_t)f * DD + e0 + e) * DD + d0 + td * 4] = o;
    }
  }
}

// ---------------- rmsnorm ----------------
__global__ __launch_bounds__(256) void k_rmsnorm(const float* __restrict__ x,
                                                 const float* __restrict__ w,
                                                 unsigned short* __restrict__ h) {
  const int row = blockIdx.x, tid = threadIdx.x;
  const float4* xr = (const float4*)(x + (size_t)row * DD);
  const float4 a = xr[tid], b = xr[tid + 256];
  float s = a.x * a.x + a.y * a.y + a.z * a.z + a.w * a.w +
            b.x * b.x + b.y * b.y + b.z * b.z + b.w * b.w;
#pragma unroll
  for (int m = 32; m; m >>= 1) s += __shfl_xor(s, m);
  __shared__ float part[4];
  if ((tid & 63) == 0) part[tid >> 6] = s;
  __syncthreads();
  const float inv = rsqrtf((part[0] + part[1] + part[2] + part[3]) * (1.f / DD) + EPS_F);
  const float4* wr = (const float4*)w;
  const float4 w0 = wr[tid], w1 = wr[tid + 256];
  ushort4 o0, o1;
  o0.x = f2bf(a.x * inv * w0.x); o0.y = f2bf(a.y * inv * w0.y);
  o0.z = f2bf(a.z * inv * w0.z); o0.w = f2bf(a.w * inv * w0.w);
  o1.x = f2bf(b.x * inv * w1.x); o1.y = f2bf(b.y * inv * w1.y);
  o1.z = f2bf(b.z * inv * w1.z); o1.w = f2bf(b.w * inv * w1.w);
  ushort4* hd = (ushort4*)(h + (size_t)row * DD);
  hd[tid] = o0;
  hd[tid + 256] = o1;
}

// ---------------- ring-4 pipelined GEMM ----------------
// out[t][n] (+)= act( sum_k A[t][k]*B[n][k] );  A:[M][2048] bf16, B:[N][2048] bf16.
// BM=128, BN=256, BK=32, 8 waves (2Mx4N), per-wave 64x64 (acc 4x4 frags).
// LDS ring of 4 K-tiles: A 4x8KB + B 4x16KB = 96KB. One phase per K-tile:
//   { 8x ds_read_b128 (tile t) | stage tile t+3 (3 gload_lds16) | vmcnt(6) |
//     barrier | setprio(1) 16x MFMA setprio(0) | barrier }
// vmcnt(6): stages for t+2,t+3 (6 loads) may stay in flight; tile t+1 guaranteed
// landed (own-wave drain + barrier => cross-wave). Stage(t+4) is issued only after
// barrier2(t), by which point all waves' ds_reads of slot(t) completed (their MFMAs
// consumed them before barrier2) -> no overwrite race.
// Swizzle: LDS slot s holds global k-group s ^ ((row>>1)&3): read 16-lane groups
// spread 2-way max (free). Pre-swizzled global source, linear gload_lds dest.
// ACT: 0 = C += v, 1 = C += silu(v), 2 = C = v
template <int ACT>
__global__ __launch_bounds__(512, 2) void k_gemm(const unsigned short* __restrict__ A,
                                                 const unsigned short* __restrict__ B,
                                                 float* __restrict__ C, const int ldc) {
  __shared__ unsigned short lsA[4][4096];   // [slot][128 rows][32 k] swizzled
  __shared__ unsigned short lsB[4][8192];   // [slot][256 rows][32 k] swizzled
  const int tid = threadIdx.x;
  const int lane = tid & 63;
  const int wave = tid >> 6;
  const int wm = wave >> 2, wn = wave & 3;
  // bijective XCD-aware swizzle (gridDim.x % 8 == 0 for both grids)
  const int bid = blockIdx.x;
  const int swz = (bid & 7) * (gridDim.x >> 3) + (bid >> 3);
  const int t0 = (swz & 31) * 128;   // M = 4096 -> 32 m-tiles always
  const int n0 = (swz >> 5) * 256;
  const unsigned short* Ab = A + (size_t)t0 * DD;
  const unsigned short* Bb = B + (size_t)n0 * DD;
  // staging coords (per thread): row = tid>>2, slot = tid&3, pre-swizzled k-group
  const int srow = tid >> 2;
  const int scol = ((tid & 3) ^ ((tid >> 3) & 3)) * 8;
  // read coords (per lane)
  const int fr = lane & 15, g = lane >> 4;
  const int xk = (g ^ ((fr >> 1) & 3)) << 3;      // swizzled elem offset in row
  const int arow = (wm * 64 + fr) * 32 + xk;      // + mi*512
  const int brow = (wn * 64 + fr) * 32 + xk;      // + ni*512

#define STAGE(tile)                                                                   \
  {                                                                                   \
    const int _q = (tile) & 3;                                                        \
    const size_t _kb = (size_t)(tile) * 32 + scol;                                    \
    gload_lds16(Ab + (size_t)srow * DD + _kb,         &lsA[_q][tid * 8]);             \
    gload_lds16(Bb + (size_t)srow * DD + _kb,         &lsB[_q][tid * 8]);             \
    gload_lds16(Bb + (size_t)(128 + srow) * DD + _kb, &lsB[_q][4096 + tid * 8]);      \
  }

  f32x4 acc[4][4];
#pragma unroll
  for (int i = 0; i < 4; ++i)
#pragma unroll
    for (int j = 0; j < 4; ++j) acc[i][j] = (f32x4){0.f, 0.f, 0.f, 0.f};

  const int NT = DD / 32;  // 64 K-tiles
  // prologue: stage tiles 0,1,2 (9 loads); wait oldest 3 (tile 0)
  STAGE(0);
  STAGE(1);
  STAGE(2);
  asm volatile("s_waitcnt vmcnt(6)" ::: "memory");
  __builtin_amdgcn_s_barrier();

  for (int t = 0; t < NT; ++t) {
    const int q = t & 3;
    bf16x8 af[4], bg[4];
#pragma unroll
    for (int mi = 0; mi < 4; ++mi) af[mi] = *(const bf16x8*)&lsA[q][arow + mi * 512];
#pragma unroll
    for (int ni = 0; ni < 4; ++ni) bg[ni] = *(const bf16x8*)&lsB[q][brow + ni * 512];
    if (t + 3 < NT) STAGE(t + 3);
    if (t < NT - 3)       asm volatile("s_waitcnt vmcnt(6)" ::: "memory");
    else if (t == NT - 3) asm volatile("s_waitcnt vmcnt(3)" ::: "memory");
    else                  asm volatile("s_waitcnt vmcnt(0)" ::: "memory");
    __builtin_amdgcn_s_barrier();
    __builtin_amdgcn_s_setprio(1);
#pragma unroll
    for (int mi = 0; mi < 4; ++mi)
#pragma unroll
      for (int ni = 0; ni < 4; ++ni)
        acc[mi][ni] = __builtin_amdgcn_mfma_f32_16x16x32_bf16(af[mi], bg[ni],
                                                              acc[mi][ni], 0, 0, 0);
    __builtin_amdgcn_s_setprio(0);
    __builtin_amdgcn_s_barrier();
  }
#undef STAGE

  const int orow = t0 + wm * 64 + g * 4;
  const int ocol = n0 + wn * 64 + fr;
#pragma unroll
  for (int mi = 0; mi < 4; ++mi)
#pragma unroll
    for (int ni = 0; ni < 4; ++ni)
#pragma unroll
      for (int j = 0; j < 4; ++j) {
        const size_t idx = (size_t)(orow + mi * 16 + j) * ldc + (ocol + ni * 16);
        const float v = acc[mi][ni][j];
        if (ACT == 0)      C[idx] += v;
        else if (ACT == 1) C[idx] += v / (1.f + __expf(-v));
        else               C[idx] = v;
      }
}

// ---------------- f32 -> bf16 bulk convert ----------------
__global__ void k_cvt(const float* __restrict__ in, unsigned short* __restrict__ out, int n4) {
  int i = blockIdx.x * blockDim.x + threadIdx.x;
  const int stride = gridDim.x * blockDim.x;
  for (; i < n4; i += stride) {
    const float4 v = ((const float4*)in)[i];
    ushort4 o;
    o.x = f2bf(v.x); o.y = f2bf(v.y); o.z = f2bf(v.z); o.w = f2bf(v.w);
    ((ushort4*)out)[i] = o;
  }
}

extern "C" void kernel_launch(void* const* d_in, const int* in_sizes, int n_in,
                              void* d_out, int out_size, void* d_ws, size_t ws_size,
                              hipStream_t stream) {
  (void)in_sizes; (void)n_in; (void)out_size; (void)ws_size;
  const int* tokens = (const int*)d_in[0];
  const float* hr = (const float*)d_in[1];
  const float* hi = (const float*)d_in[2];
  const float* kar = (const float*)d_in[3];
  const float* kai = (const float*)d_in[4];
  const float* kbr = (const float*)d_in[5];
  const float* kbi = (const float*)d_in[6];
  const float* lscale = (const float*)d_in[7];
  const float* norm_w = (const float*)d_in[8];
  const float* embed = (const float*)d_in[9];
  const float* lm = (const float*)d_in[10];
  const float* fnw = (const float*)d_in[11];
  float* out = (float*)d_out;
  char* ws = (char*)d_ws;

  // ws layout: W bf16 [24][2048][2048] @0 (192 MiB); h bf16 [4096][2048] after.
  // lm_bf16 overlays W (dead after last layer). x (f32) lives in d_out (dead
  // before the final GEMM overwrites all of d_out).
  unsigned short* W = (unsigned short*)ws;
  unsigned short* h = (unsigned short*)(ws + 201326592);
  unsigned short* lmb = W;
  float* x = out;

  k_gather<<<NROWS, 256, 0, stream>>>(tokens, embed, x);
  k_wrec<<<dim3(32, 32), 256, 0, stream>>>(hr, hi, kar, kai, kbr, kbi, lscale, W);
  for (int l = 0; l < 12; ++l) {
    k_rmsnorm<<<NROWS, 256, 0, stream>>>(x, norm_w + (size_t)l * 2 * DD, h);
    k_gemm<0><<<256, 512, 0, stream>>>(h, W + (size_t)(2 * l) * DD * DD, x, DD);
    k_rmsnorm<<<NROWS, 256, 0, stream>>>(x, norm_w + (size_t)l * 2 * DD + DD, h);
    k_gemm<1><<<256, 512, 0, stream>>>(h, W + (size_t)(2 * l + 1) * DD * DD, x, DD);
  }
  k_rmsnorm<<<NROWS, 256, 0, stream>>>(x, fnw, h);
  k_cvt<<<2048, 256, 0, stream>>>(lm, lmb, VOCAB_N * DD / 4);
  k_gemm<2><<<4000, 512, 0, stream>>>(h, lmb, out, VOCAB_N);
}